// Round 1
// baseline (324.699 us; speedup 1.0000x reference)
//
#include <hip/hip_runtime.h>
#include <hip/hip_bf16.h>
#include <cstdint>

#define S_LEN 2048
#define DIM   256
#define NBAT  8
#define NFE   8192
#define NEDGE (NBAT*NFE)   // 65536
#define HID   512
#define INDIM 768

// ---- workspace layout (bytes) ----
#define OFF_AGG   0u
#define OFF_POOL  16777216u
#define OFF_CNT   16785408u
#define OFF_NODES 16785664u
#define OFF_PRED  17834240u
#define OFF_ROLE  18358528u
#define OFF_W1P   18392576u
#define OFF_W2P   19179008u
#define OFF_FWD   19441152u
#define OFF_REV   19703296u
#define ZERO_BYTES 16785664u   // agg + pooled + counters

typedef short bshort8 __attribute__((ext_vector_type(8)));
typedef float floatx4 __attribute__((ext_vector_type(4)));

__device__ __forceinline__ float gelu_f(float x) {
  return 0.5f * x * (1.0f + erff(x * 0.70710678118654752f));
}
__device__ __forceinline__ ushort f2bf(float v) {
  __hip_bfloat16 h = __float2bfloat16(v);
  return *reinterpret_cast<ushort*>(&h);
}

// ---------------- prep: f32 tables -> bf16 ----------------
__global__ void prep_tables(const float* __restrict__ pos, const float* __restrict__ pred,
                            const float* __restrict__ role,
                            ushort* __restrict__ nodesT, ushort* __restrict__ predT,
                            ushort* __restrict__ roleT) {
  int i = blockIdx.x * blockDim.x + threadIdx.x;
  const int NN = S_LEN * DIM;           // 524288
  const int NP = 1024 * DIM;            // 262144
  if (i < NN) nodesT[i] = f2bf(pos[i]);
  else if (i < NN + NP) { int j = i - NN; predT[j] = f2bf(pred[j]); }
  else { int j = i - NN - NP; if (j < 66 * DIM) roleT[j] = f2bf(role[j]); }
}

// pack weights into MFMA B-fragment friendly layout: Wp[(k/8)][n][k%8]
__global__ void prep_w(const float* __restrict__ w1, const float* __restrict__ w2,
                       ushort* __restrict__ W1p, ushort* __restrict__ W2p) {
  int i = blockIdx.x * blockDim.x + threadIdx.x;
  const int N1 = INDIM * HID;           // 393216
  if (i < N1) {
    int k = i >> 9, n = i & 511;
    W1p[(((k >> 3) << 9) + n) * 8 + (k & 7)] = f2bf(w1[i]);
  } else {
    int j = i - N1;                     // [0, 131072)
    int k = j >> 8, n = j & 255;
    W2p[(((k >> 3) << 8) + n) * 8 + (k & 7)] = f2bf(w2[j]);
  }
}

// ---------------- worklist build ----------------
__global__ void build_lists(const int* __restrict__ mask, const int* __restrict__ is_role,
                            const int* __restrict__ add_rev,
                            int* __restrict__ fwd, int* __restrict__ rev, int* __restrict__ cnt) {
  int e = blockIdx.x * blockDim.x + threadIdx.x;
  if (e >= NEDGE) return;
  if (mask[e]) {
    int p = atomicAdd(&cnt[0], 1);
    fwd[p] = e;
    if (!is_role[e] && add_rev[e]) {
      int q = atomicAdd(&cnt[1], 1);
      rev[q] = e;
    }
  }
}

// ---------------- fused edge MLP + scatter ----------------
// 64 rows/tile, 512 threads (8 waves, 2x4 wave grid)
#define XSTR 1552   // 768*2 + 16 pad
#define HSTR 1040   // 512*2 + 16 pad
__global__ __launch_bounds__(512, 1)
void mlp_kernel(const int* __restrict__ cnt, const int* __restrict__ fwd, const int* __restrict__ rev,
                const int* __restrict__ a0, const int* __restrict__ a1,
                const int* __restrict__ pred_idx, const int* __restrict__ role_idx,
                const int* __restrict__ is_role,
                const ushort* __restrict__ nodesT, const ushort* __restrict__ predT,
                const ushort* __restrict__ roleT,
                const ushort* __restrict__ W1p, const ushort* __restrict__ W2p,
                const float* __restrict__ b1, const float* __restrict__ b2,
                float* __restrict__ agg) {
  __shared__ __align__(16) unsigned char smem[64 * XSTR];
  __shared__ int ltgt[64];
  __shared__ int lbat[64];

  const int tid = threadIdx.x;
  const int nf = cnt[0], nr = cnt[1];
  const int total = nf + nr;
  const int row0 = blockIdx.x * 64;
  if (row0 >= total) return;

  // --- meta: target node + batch per row ---
  if (tid < 64) {
    int grow = row0 + tid;
    int tgt = -1, bb = 0;
    if (grow < total) {
      bool rv = grow >= nf;
      int e = rv ? rev[grow - nf] : fwd[grow];
      bb = e >> 13;
      tgt = rv ? a0[e] : (is_role[e] ? a0[e] : a1[e]);
    }
    ltgt[tid] = tgt; lbat[tid] = bb;
  }
  // --- gather x rows (bf16) into LDS: [n0|pe|third] fwd, [n1|pe|n0] rev ---
  {
    int r = tid >> 3, sub = tid & 7;
    int grow = row0 + r;
    const ushort *s0, *s1, *s2;
    if (grow < total) {
      bool rv = grow >= nf;
      int e = rv ? rev[grow - nf] : fwd[grow];
      int A0 = a0[e], A1 = a1[e], pi = pred_idx[e];
      s1 = predT + pi * DIM;
      if (rv) { s0 = nodesT + A1 * DIM; s2 = nodesT + A0 * DIM; }
      else {
        s0 = nodesT + A0 * DIM;
        s2 = is_role[e] ? (roleT + role_idx[e] * DIM) : (nodesT + A1 * DIM);
      }
    } else { s0 = s1 = s2 = nodesT; }
    unsigned char* xrow = smem + r * XSTR;
#pragma unroll
    for (int c = 0; c < 12; ++c) {
      int ch = sub * 12 + c;
      int col = ch * 8;
      const ushort* src = (col < 256) ? (s0 + col) : (col < 512) ? (s1 + col - 256) : (s2 + col - 512);
      *reinterpret_cast<uint4*>(xrow + ch * 16) = *reinterpret_cast<const uint4*>(src);
    }
  }
  __syncthreads();

  const int lane = tid & 63, wave = tid >> 6;
  const int wm = wave >> 2, wn = wave & 3;
  const int l15 = lane & 15, kb = lane >> 4;

  // --- GEMM1: [64x768] @ [768x512], wave -> 32x128 ---
  floatx4 acc1[2][8];
#pragma unroll
  for (int fm = 0; fm < 2; ++fm)
#pragma unroll
    for (int fn = 0; fn < 8; ++fn) acc1[fm][fn] = (floatx4){0.f, 0.f, 0.f, 0.f};

  for (int k0 = 0; k0 < INDIM; k0 += 32) {
    bshort8 av[2];
#pragma unroll
    for (int fm = 0; fm < 2; ++fm)
      av[fm] = *reinterpret_cast<const bshort8*>(smem + (wm * 32 + fm * 16 + l15) * XSTR + (k0 + kb * 8) * 2);
    const ushort* wp = W1p + (((k0 >> 3) + kb) * 512 + wn * 128 + l15) * 8;
#pragma unroll
    for (int fn = 0; fn < 8; ++fn) {
      bshort8 bv = *reinterpret_cast<const bshort8*>(wp + fn * 128);
      acc1[0][fn] = __builtin_amdgcn_mfma_f32_16x16x32_bf16(av[0], bv, acc1[0][fn], 0, 0, 0);
      acc1[1][fn] = __builtin_amdgcn_mfma_f32_16x16x32_bf16(av[1], bv, acc1[1][fn], 0, 0, 0);
    }
  }
  __syncthreads();   // done reading X; reuse smem for H

  // --- bias + gelu -> H (bf16) in LDS ---
#pragma unroll
  for (int fn = 0; fn < 8; ++fn) {
    int n = wn * 128 + fn * 16 + l15;
    float bias = b1[n];
#pragma unroll
    for (int fm = 0; fm < 2; ++fm) {
#pragma unroll
      for (int rg = 0; rg < 4; ++rg) {
        int m = wm * 32 + fm * 16 + kb * 4 + rg;
        float v = gelu_f(acc1[fm][fn][rg] + bias);
        *reinterpret_cast<ushort*>(smem + m * HSTR + n * 2) = f2bf(v);
      }
    }
  }
  __syncthreads();

  // --- GEMM2: [64x512] @ [512x256], wave -> 32x64 ---
  floatx4 acc2[2][4];
#pragma unroll
  for (int fm = 0; fm < 2; ++fm)
#pragma unroll
    for (int fn = 0; fn < 4; ++fn) acc2[fm][fn] = (floatx4){0.f, 0.f, 0.f, 0.f};

  for (int k0 = 0; k0 < HID; k0 += 32) {
    bshort8 av[2];
#pragma unroll
    for (int fm = 0; fm < 2; ++fm)
      av[fm] = *reinterpret_cast<const bshort8*>(smem + (wm * 32 + fm * 16 + l15) * HSTR + (k0 + kb * 8) * 2);
    const ushort* wp = W2p + (((k0 >> 3) + kb) * 256 + wn * 64 + l15) * 8;
#pragma unroll
    for (int fn = 0; fn < 4; ++fn) {
      bshort8 bv = *reinterpret_cast<const bshort8*>(wp + fn * 128);
      acc2[0][fn] = __builtin_amdgcn_mfma_f32_16x16x32_bf16(av[0], bv, acc2[0][fn], 0, 0, 0);
      acc2[1][fn] = __builtin_amdgcn_mfma_f32_16x16x32_bf16(av[1], bv, acc2[1][fn], 0, 0, 0);
    }
  }

  // --- scatter: msg + b2 -> atomic add into agg[b][tgt][:] ---
#pragma unroll
  for (int fn = 0; fn < 4; ++fn) {
    int n = wn * 64 + fn * 16 + l15;
    float bias = b2[n];
#pragma unroll
    for (int fm = 0; fm < 2; ++fm) {
#pragma unroll
      for (int rg = 0; rg < 4; ++rg) {
        int m = wm * 32 + fm * 16 + kb * 4 + rg;
        int tgt = ltgt[m];
        if (tgt >= 0) {
          float v = acc2[fm][fn][rg] + bias;
          unsafeAtomicAdd(&agg[((lbat[m] << 11) + tgt) * DIM + n], v);
        }
      }
    }
  }
}

// ---------------- LayerNorm + mean pool ----------------
__global__ void ln_pool(const float* __restrict__ pos, const float* __restrict__ agg,
                        const float* __restrict__ g, const float* __restrict__ be,
                        float* __restrict__ pooled_sum) {
  __shared__ float r2[16];
  const int b = blockIdx.x >> 7;
  const int sb = blockIdx.x & 127;
  const int t = threadIdx.x;
  const float gg = g[t], bb = be[t];
  const int wv = t >> 6;
  float psum = 0.f;
#pragma unroll 1
  for (int i = 0; i < 16; ++i) {
    int s = sb * 16 + i;
    float x = pos[s * DIM + t] + agg[((b << 11) + s) * DIM + t];
    float a = x, q = x * x;
#pragma unroll
    for (int o = 32; o > 0; o >>= 1) { a += __shfl_xor(a, o); q += __shfl_xor(q, o); }
    if ((t & 63) == 0) { r2[wv * 2] = a; r2[wv * 2 + 1] = q; }
    __syncthreads();
    a = r2[0] + r2[2] + r2[4] + r2[6];
    q = r2[1] + r2[3] + r2[5] + r2[7];
    __syncthreads();
    float mu = a * (1.f / 256.f);
    float var = q * (1.f / 256.f) - mu * mu;
    float y = (x - mu) * rsqrtf(var + 1e-5f) * gg + bb;
    psum += y;
  }
  unsafeAtomicAdd(&pooled_sum[(b << 8) + t], psum);
}

// ---------------- final tiny MLP (one block) ----------------
__global__ void final_mlp(const float* __restrict__ pooled_sum,
                          const float* __restrict__ lw1, const float* __restrict__ lb1,
                          const float* __restrict__ lw2, const float* __restrict__ lb2,
                          float* __restrict__ out) {
  __shared__ float pl[8 * 256];
  __shared__ float hl[8 * 256];
  const int t = threadIdx.x;
#pragma unroll
  for (int r = 0; r < 8; ++r) pl[r * 256 + t] = pooled_sum[r * 256 + t] * (1.f / 2048.f);
  __syncthreads();
  float acc[8];
#pragma unroll
  for (int r = 0; r < 8; ++r) acc[r] = lb1[t];
  for (int d = 0; d < 256; ++d) {
    float w = lw1[d * 256 + t];
#pragma unroll
    for (int r = 0; r < 8; ++r) acc[r] = fmaf(pl[r * 256 + d], w, acc[r]);
  }
#pragma unroll
  for (int r = 0; r < 8; ++r) hl[r * 256 + t] = gelu_f(acc[r]);
  __syncthreads();
#pragma unroll
  for (int r = 0; r < 8; ++r) acc[r] = lb2[t];
  for (int d = 0; d < 256; ++d) {
    float w = lw2[d * 256 + t];
#pragma unroll
    for (int r = 0; r < 8; ++r) acc[r] = fmaf(hl[r * 256 + d], w, acc[r]);
  }
#pragma unroll
  for (int r = 0; r < 8; ++r) out[r * 256 + t] = acc[r];
}

extern "C" void kernel_launch(void* const* d_in, const int* in_sizes, int n_in,
                              void* d_out, int out_size, void* d_ws, size_t ws_size,
                              hipStream_t stream) {
  const float* pos_emb  = (const float*)d_in[0];
  const float* pred_emb = (const float*)d_in[1];
  const float* role_emb = (const float*)d_in[2];
  const float* w1   = (const float*)d_in[3];
  const float* b1   = (const float*)d_in[4];
  const float* w2   = (const float*)d_in[5];
  const float* b2   = (const float*)d_in[6];
  const float* ln_g = (const float*)d_in[7];
  const float* ln_b = (const float*)d_in[8];
  const float* lw1  = (const float*)d_in[9];
  const float* lb1  = (const float*)d_in[10];
  const float* lw2  = (const float*)d_in[11];
  const float* lb2  = (const float*)d_in[12];
  const int* pred_idx = (const int*)d_in[13];
  const int* a0       = (const int*)d_in[14];
  const int* a1       = (const int*)d_in[15];
  const int* role_idx = (const int*)d_in[16];
  const int* is_role  = (const int*)d_in[17];
  const int* add_rev  = (const int*)d_in[18];
  const int* mask     = (const int*)d_in[19];

  unsigned char* ws = (unsigned char*)d_ws;
  float*  agg    = (float*)(ws + OFF_AGG);
  float*  pooled = (float*)(ws + OFF_POOL);
  int*    cnt    = (int*)(ws + OFF_CNT);
  ushort* nodesT = (ushort*)(ws + OFF_NODES);
  ushort* predT  = (ushort*)(ws + OFF_PRED);
  ushort* roleT  = (ushort*)(ws + OFF_ROLE);
  ushort* W1p    = (ushort*)(ws + OFF_W1P);
  ushort* W2p    = (ushort*)(ws + OFF_W2P);
  int*    fwd    = (int*)(ws + OFF_FWD);
  int*    rev    = (int*)(ws + OFF_REV);

  hipMemsetAsync(ws, 0, ZERO_BYTES, stream);
  prep_tables<<<3138, 256, 0, stream>>>(pos_emb, pred_emb, role_emb, nodesT, predT, roleT);
  prep_w<<<2048, 256, 0, stream>>>(w1, w2, W1p, W2p);
  build_lists<<<256, 256, 0, stream>>>(mask, is_role, add_rev, fwd, rev, cnt);
  mlp_kernel<<<2048, 512, 0, stream>>>(cnt, fwd, rev, a0, a1, pred_idx, role_idx, is_role,
                                       nodesT, predT, roleT, W1p, W2p, b1, b2, agg);
  ln_pool<<<1024, 256, 0, stream>>>(pos_emb, agg, ln_g, ln_b, pooled);
  final_mlp<<<1, 256, 0, stream>>>(pooled, lw1, lb1, lw2, lb2, (float*)d_out);
}